// Round 5
// baseline (473.034 us; speedup 1.0000x reference)
//
#include <hip/hip_runtime.h>
#include <hip/hip_bf16.h>
#include <type_traits>

constexpr int B_ = 8, C_ = 256, P_ = 64, H_ = 64, W_ = 64, HW_ = 4096;

typedef __attribute__((ext_vector_type(8))) short short8;   // 8 bf16
typedef __attribute__((ext_vector_type(4))) short short4v;  // 4 bf16 (8 B)
typedef __attribute__((ext_vector_type(4))) float f32x4;

__device__ __forceinline__ short bfbits(float f) {
    __hip_bfloat16 h = __float2bfloat16(f);
    return *reinterpret_cast<short*>(&h);
}
__device__ __forceinline__ float bf2f(short s) {
    __hip_bfloat16 h = *reinterpret_cast<__hip_bfloat16*>(&s);
    return (float)h;
}

// async global->LDS, 16B per lane; dst must be wave-uniform base (HW adds lane*16)
#define GLL16(gsrc, ldst)                                                      \
    __builtin_amdgcn_global_load_lds(                                         \
        (const __attribute__((address_space(1))) void*)(gsrc),                \
        (__attribute__((address_space(3))) void*)(ldst), 16, 0, 0)

// ---------------------------------------------------------------------------
// Fragment-linear packed layouts (one wave-load = base + lane*16, contiguous):
//   xtP/xcP [b][tile16][kc2][lane64]x16B : chunk = x[row=tile*16+lm][p=kc*32+lq*8..+8]
//   xbP     [b][g128][ct16][lane64]x16B  : chunk = xb[c=ct*16+lm][m=g*32+lq*8..+8]
//   wbP     [tap9][cb8][cot16][lane64]x16B: chunk = w[co=cot*16+lm][ci=cb*32+lq*8..+8]
//   xPk/yPk [b][cbk4][hs66][512 chunks]  : chunk k -> (row=k/8+1, slot=k%8);
//       content = bf16 x[ci = cbk*64 + (slot^(row&7))*8 .. +8][hh=hs-1][w=row-1]
//       (hs 0 and 65 are zero guard rows; slot-XOR = LDS bank swizzle)
// ---------------------------------------------------------------------------

// K0: weight prep, fp32 OIHW -> fragment-linear bf16 wbP. 288 blocks.
__global__ __launch_bounds__(256) void k_prep_w(
    const float* __restrict__ w, short8* __restrict__ wbP)
{
    const int idx = blockIdx.x * 256 + threadIdx.x;      // < 9*8*16*64 = 73728
    const int lane = idx & 63, cot = (idx >> 6) & 15;
    const int cb = (idx >> 10) & 7, tap = idx >> 13;
    const int lm = lane & 15, lq = lane >> 4;
    const int co = cot * 16 + lm, ci0 = cb * 32 + lq * 8;
    short8 v;
#pragma unroll
    for (int k = 0; k < 8; ++k)
        v[k] = bfbits(w[(co * 256 + ci0 + k) * 9 + tap]);
    wbP[idx] = v;
}

// K0b: xb [B][C][HW] bf16 -> fragment-linear xbP. 4096 blocks.
__global__ __launch_bounds__(256) void k_pack_xb(
    const __hip_bfloat16* __restrict__ xb, short8* __restrict__ xbP)
{
    const int tid = blockIdx.x * 256 + threadIdx.x;
    const int lane = tid & 63, wid = tid >> 6;           // wid < 8*128*16
    const int ct = wid & 15, g = (wid >> 4) & 127, b = wid >> 11;
    const int c = ct * 16 + (lane >> 2);
    const int mo = g * 32 + (lane & 3) * 8;
    const short8 v = *reinterpret_cast<const short8*>(
        &xb[((size_t)(b * 256 + c)) * HW_ + mo]);
    xbP[(size_t)wid * 64 + (lane & 3) * 16 + (lane >> 2)] = v;
}

// ---------------------------------------------------------------------------
// K0c: pack fp32 [B][C][HW] -> conv3x3 swizzled-fragment bf16 xPk.
// Wave handles one (b, cbk, hs): 64 coalesced 256B loads, 128B contiguous
// store per lane. Guard rows (hs=0,65) write zeros. 528 blocks.
// ---------------------------------------------------------------------------
__global__ __launch_bounds__(256) void k_pack_x(
    const float* __restrict__ src, short8* __restrict__ dst)
{
    const int tid = blockIdx.x * 256 + threadIdx.x;
    const int lane = tid & 63, wid = tid >> 6;           // wid < 8*4*66 = 2112
    const int hs = wid % 66, cbk = (wid / 66) & 3, b = wid / 264;
    const int hh = hs - 1;
    short8 v[8];
    if (hh < 0 || hh > 63) {
#pragma unroll
        for (int s = 0; s < 8; ++s)
            v[s] = short8{0, 0, 0, 0, 0, 0, 0, 0};
    } else {
        const float* sp = src + (size_t)b * C_ * HW_ + hh * 64 + lane;
#pragma unroll
        for (int s = 0; s < 8; ++s) {
            const int g = s ^ ((lane + 1) & 7);          // row = lane+1
#pragma unroll
            for (int j = 0; j < 8; ++j)
                v[s][j] = bfbits(sp[(size_t)(cbk * 64 + g * 8 + j) * HW_]);
        }
    }
    short8* dp = dst + (size_t)wid * 512 + lane * 8;     // lane-contiguous 128B
#pragma unroll
    for (int s = 0; s < 8; ++s) dp[s] = v[s];
}

// ---------------------------------------------------------------------------
// K4': y = x + O*(1/Z) fused DIRECTLY into the packed conv layout (replaces
// k_add + a second pack pass; kills the 32MB fp32 y round-trip). Same
// decode as k_pack_x; O read via flat reinterpretation (same linear index).
// ---------------------------------------------------------------------------
__global__ __launch_bounds__(256) void k_add_pack(
    const float* __restrict__ x, const float* __restrict__ O,
    const float* __restrict__ Z, short8* __restrict__ dst)
{
    const int tid = blockIdx.x * 256 + threadIdx.x;
    const int lane = tid & 63, wid = tid >> 6;           // wid < 2112
    const int hs = wid % 66, cbk = (wid / 66) & 3, b = wid / 264;
    const int hh = hs - 1;
    short8 v[8];
    if (hh < 0 || hh > 63) {
#pragma unroll
        for (int s = 0; s < 8; ++s)
            v[s] = short8{0, 0, 0, 0, 0, 0, 0, 0};
    } else {
        const float invZ = 1.0f / Z[b];
        const float* xp = x + (size_t)b * C_ * HW_ + hh * 64 + lane;
        const float* op = O + (size_t)b * HW_ * C_ + hh * 64 + lane;
#pragma unroll
        for (int s = 0; s < 8; ++s) {
            const int g = s ^ ((lane + 1) & 7);
#pragma unroll
            for (int j = 0; j < 8; ++j) {
                const size_t off = (size_t)(cbk * 64 + g * 8 + j) * HW_;
                v[s][j] = bfbits(fmaf(op[off], invZ, xp[off]));
            }
        }
    }
    short8* dp = dst + (size_t)wid * 512 + lane * 8;
#pragma unroll
    for (int s = 0; s < 8; ++s) dp[s] = v[s];
}

// ---------------------------------------------------------------------------
// K1: 1x1 convs, p-quarter split (grid 16x8x8). Epilogue writes hi/lo bf16
// directly in fragment-linear xtP/xcP order.
// ---------------------------------------------------------------------------
__global__ __launch_bounds__(256) void k_conv1x1(
    const float* __restrict__ x,
    const float* __restrict__ w_top, const float* __restrict__ b_top,
    const float* __restrict__ w_cen, const float* __restrict__ b_cen,
    short8* __restrict__ xtPh, short8* __restrict__ xtPl,
    short8* __restrict__ xcPh, short8* __restrict__ xcPl)
{
    const int b = blockIdx.z;
    const int n = blockIdx.x * 256 + threadIdx.x;
    const int conv = blockIdx.y >> 2, pq = blockIdx.y & 3;
    const int p0 = pq * 16;
    const float* w    = conv ? w_cen : w_top;
    const float* bias = conv ? b_cen : b_top;
    short8* oh = conv ? xcPh : xtPh;
    short8* ol = conv ? xcPl : xtPl;

    const float* xp = x + (size_t)b * C_ * HW_ + n;
    float acc[16];
#pragma unroll
    for (int p = 0; p < 16; ++p) acc[p] = 0.f;

    for (int c = 0; c < C_; c += 4) {
        const float xv0 = xp[(size_t)(c + 0) * HW_];
        const float xv1 = xp[(size_t)(c + 1) * HW_];
        const float xv2 = xp[(size_t)(c + 2) * HW_];
        const float xv3 = xp[(size_t)(c + 3) * HW_];
#pragma unroll
        for (int p = 0; p < 16; ++p) {
            const float4 wv = *reinterpret_cast<const float4*>(&w[(p0 + p) * C_ + c]);
            float a = acc[p];
            a = fmaf(wv.x, xv0, a);
            a = fmaf(wv.y, xv1, a);
            a = fmaf(wv.z, xv2, a);
            a = fmaf(wv.w, xv3, a);
            acc[p] = a;
        }
    }
    const int nt = n >> 4, lmn = n & 15;
    const size_t obase = ((size_t)(b * 256 + nt) * 2 + (pq >> 1)) * 64 + lmn;
#pragma unroll
    for (int jj = 0; jj < 2; ++jj) {
        short8 vh, vl;
#pragma unroll
        for (int k = 0; k < 8; ++k) {
            const float v = acc[jj * 8 + k] + bias[p0 + jj * 8 + k];
            const short hb = bfbits(v);
            vh[k] = hb;
            vl[k] = bfbits(v - bf2f(hb));   // residual for hi/lo split
        }
        const size_t idx = obase + (size_t)(((pq & 1) * 2 + jj) * 16);
        oh[idx] = vh;
        ol[idx] = vl;
    }
}

// ---------------------------------------------------------------------------
// K2/K5: 3x3 conv, R12: input from swizzled packed xPk. Staging is now pure
// global_load_lds (no cvt, no scalar ds_write), double-buffered over 4 K=64
// steps with ONE barrier + vmcnt wait per step. Fragment ds_read_b128 is
// bank-swizzled (slot ^= row&7 on 128B rows) -> ~2-way = free. 8 waves cover
// all 256 co; grid 512, b==XCD; LDS 49.5KB, 2 blocks/CU.
// ---------------------------------------------------------------------------
template <typename OT>
__global__ __launch_bounds__(512, 4) void k_conv3x3_mfma(
    const short8* __restrict__ xPk, const short8* __restrict__ wbP,
    const float* __restrict__ bias, OT* __restrict__ out)
{
    __shared__ __align__(16) char Xs[2][3][66 * 128];   // [buf][r-tile][row][128B]
    const int lin = blockIdx.x;                 // 0..511
    const int b = lin & 7, h = lin >> 3;        // b == XCD
    const int t = threadIdx.x;
    const int wave = t >> 6, lane = t & 63;
    const int lm = lane & 15, lq = lane >> 4;
    const int cobase = wave * 32;
    const int cot0 = wave * 2;                  // co-tile index base (co/16)

    // zero w-halo rows (row 0 = w:-1, row 65 = w:64) of all tiles/buffers once
    if (t < 384) {
        const int bufi = t / 192, rem = t % 192;
        const int rs = rem / 32, col = rem % 32;        // rs 0..5
        const int tl = rs >> 1, row = (rs & 1) ? 65 : 0;
        *reinterpret_cast<int*>(&Xs[bufi][tl][row * 128 + col * 4]) = 0;
    }

    auto stage = [&](int cbk, int bufi) {
#pragma unroll
        for (int j = 0; j < 3; ++j) {
            const int q = wave * 3 + j;          // 0..23 chunks of 1KB
            const int r = q >> 3, c = q & 7;
            const short8* src = xPk +
                ((size_t)((b * 4 + cbk) * 66 + h + r) * 512 + c * 64 + lane);
            GLL16(src, &Xs[bufi][r][128 + c * 1024]);   // rows 1..64
        }
    };

    f32x4 acc[4][2];   // [n_tile][co_tile]
#pragma unroll
    for (int i = 0; i < 4; ++i)
#pragma unroll
        for (int j = 0; j < 2; ++j) acc[i][j] = f32x4{0.f, 0.f, 0.f, 0.f};

    __syncthreads();                 // halo zeros visible before any read
    stage(0, 0);                     // prologue: 3 loads/wave in flight

    for (int cbk = 0; cbk < 4; ++cbk) {
        const int cur = cbk & 1;
        // only this wave's stage batch is outstanding (af loads all retired
        // by their consuming MFMAs) -> wait for cur buffer to land
        asm volatile("s_waitcnt vmcnt(0)" ::: "memory");
        __builtin_amdgcn_sched_barrier(0);
        __builtin_amdgcn_s_barrier();           // all waves' staging landed;
        __builtin_amdgcn_sched_barrier(0);      // all prev readers done
        if (cbk < 3) stage(cbk + 1, cur ^ 1);   // prefetch next K-step

#pragma unroll 3
        for (int tap = 0; tap < 9; ++tap) {
            const int dh = tap / 3;
            const int dw = tap % 3;
            const short8* wp = wbP + ((size_t)(tap * 8 + cbk * 2)) * 1024 + lane;
            short8 af[2][2];   // [kc][ct]
            af[0][0] = wp[(cot0 + 0) * 64];
            af[0][1] = wp[(cot0 + 1) * 64];
            af[1][0] = wp[1024 + (cot0 + 0) * 64];
            af[1][1] = wp[1024 + (cot0 + 1) * 64];
            short8 bf[4][2];
#pragma unroll
            for (int nt = 0; nt < 4; ++nt) {
                const int row = nt * 16 + lm + dw;
#pragma unroll
                for (int kc = 0; kc < 2; ++kc) {
                    const int s = (kc * 4 + lq) ^ (row & 7);
                    bf[nt][kc] = *reinterpret_cast<const short8*>(
                        &Xs[cur][dh][row * 128 + s * 16]);
                }
            }
#pragma unroll
            for (int nt = 0; nt < 4; ++nt)
#pragma unroll
                for (int ct = 0; ct < 2; ++ct) {
                    acc[nt][ct] = __builtin_amdgcn_mfma_f32_16x16x32_bf16(
                        af[0][ct], bf[nt][0], acc[nt][ct], 0, 0, 0);
                    acc[nt][ct] = __builtin_amdgcn_mfma_f32_16x16x32_bf16(
                        af[1][ct], bf[nt][1], acc[nt][ct], 0, 0, 0);
                }
        }
    }

#pragma unroll
    for (int nt = 0; nt < 4; ++nt) {
        const int pos = h * W_ + nt * 16 + lm;
#pragma unroll
        for (int ct = 0; ct < 2; ++ct) {
            const int co = cobase + ct * 16 + lq * 4;
#pragma unroll
            for (int r = 0; r < 4; ++r) {
                const float v = acc[nt][ct][r] + bias[co + r];
                if constexpr (std::is_same<OT, __hip_bfloat16>::value)
                    out[((size_t)(b * C_ + co + r)) * HW_ + pos] = __float2bfloat16(v);
                else
                    out[((size_t)(b * C_ + co + r)) * HW_ + pos] = v;
            }
        }
    }
}

// ---------------------------------------------------------------------------
// K3: fused attention. R10 structure (unchanged): one block per (b, 128-n
// stripe), grid 256, all 64 mt per block, double-buffered XT/XB via
// global_load_lds with counted vmcnt, S^T 2m x 4n wave split, fragment-
// linear Ps. 2 barriers/iter. LDS 114.7 KB, 1 block/CU. b == XCD.
// ---------------------------------------------------------------------------
__global__ __launch_bounds__(512, 2) void k_attn_mfma(
    const short8* __restrict__ xtPh, const short8* __restrict__ xtPl,
    const short8* __restrict__ xcPh, const short8* __restrict__ xcPl,
    const short8* __restrict__ xbP, float* __restrict__ O,
    float* __restrict__ Z)
{
    extern __shared__ __align__(16) char smem[];
    short8* XTs = (short8*)smem;                    // [2][1024]  (2 x 16 KB)
    short8* XBs = (short8*)(smem + 32768);          // [2][2048]  (2 x 32 KB)
    short8* Ps8 = (short8*)(smem + 98304);          // [8 T][2 mh][64]  16 KB
    short4v* Ps4 = (short4v*)(smem + 98304);
    float* zred = (float*)(smem + 114688);

    const int lin = blockIdx.x;                 // 0..255
    const int b = lin & 7, nblk = lin >> 3;     // b == XCD (round-robin dispatch)
    const int n0 = nblk * 128;

    const int t = threadIdx.x, wv = t >> 6, lane = t & 63;
    const int lm = lane & 15, lq = lane >> 4;
    const int mh = wv >> 2, nq2 = wv & 3;       // S^T split: m-half x n-quarter
    const int nq = wv >> 2, cq = wv & 3;        // PV split: n-half x c-quarter

    // Hoisted S^T B-frags: xc for wave's 2 n-tiles (nq2*2, nq2*2+1)
    short8 cB2[2][2][2];   // [ntile][kc][hilo]
#pragma unroll
    for (int ntile = 0; ntile < 2; ++ntile) {
        const int gt = nblk * 8 + nq2 * 2 + ntile;
        const size_t base = ((size_t)(b * 256 + gt) * 2) * 64 + lane;
        cB2[ntile][0][0] = xcPh[base];
        cB2[ntile][1][0] = xcPh[base + 64];
        cB2[ntile][0][1] = xcPl[base];
        cB2[ntile][1][1] = xcPl[base + 64];
    }
    asm volatile("s_waitcnt vmcnt(0)" ::: "memory");   // clean slate for counts

    auto stage = [&](int smt, int bufi) {
        short8* XT = XTs + bufi * 1024;
        short8* XB = XBs + bufi * 2048;
        const size_t abase = ((size_t)(b * 512 + smt * 8)) * 64;
#pragma unroll
        for (int k = 0; k < 2; ++k) {            // 2 xt chunks (issued FIRST)
            const int c = wv * 2 + k, ms = c >> 2, part = c & 3;
            const short8* src = (part < 2 ? xtPh : xtPl)
                                + abase + ms * 128 + (part & 1) * 64 + lane;
            GLL16(src, XT + c * 64);
        }
        const size_t p8 = ((size_t)(b * 2048 + smt * 32)) * 64;
#pragma unroll
        for (int k = 0; k < 4; ++k) {            // 4 xb chunks
            const int e = k * 512 + wv * 64;
            GLL16(xbP + p8 + e + lane, XB + e);
        }
    };
    stage(0, 0);                                 // prologue: 6 loads in flight

    f32x4 acc[4][4];   // O partial [n-subtile within half][c-tile within quarter]
#pragma unroll
    for (int i = 0; i < 4; ++i)
#pragma unroll
        for (int jj = 0; jj < 4; ++jj) acc[i][jj] = f32x4{0.f, 0.f, 0.f, 0.f};
    float zp = 0.f;

    for (int mt = 0; mt < 64; ++mt) {
        const int cur = mt & 1;
        // own cur-xt (oldest 2 of 6) landed; cur-xb still in flight
        asm volatile("s_waitcnt vmcnt(4)" ::: "memory");
        __builtin_amdgcn_sched_barrier(0);
        __builtin_amdgcn_s_barrier();            // all waves' xt staged; all
        __builtin_amdgcn_sched_barrier(0);       // finished prev PV reads
        // issue next tile's 6 loads into the other buffer (wrap keeps counts
        // uniform; final wrap-stage is harmless)
        stage((mt + 1) & 63, cur ^ 1);

        // ---- S^T: wave = (mh, nq2) -> 32 m x 32 n of this mt's 64x128 ----
        const short8* XT = XTs + cur * 1024;
#pragma unroll
        for (int ms2 = 0; ms2 < 2; ++ms2) {
            const int ms = mh * 2 + ms2;
            const short8 aH0 = XT[(ms * 4 + 0) * 64 + lane];
            const short8 aH1 = XT[(ms * 4 + 1) * 64 + lane];
            const short8 aL0 = XT[(ms * 4 + 2) * 64 + lane];
            const short8 aL1 = XT[(ms * 4 + 3) * 64 + lane];
#pragma unroll
            for (int ntile = 0; ntile < 2; ++ntile) {
                f32x4 s = {0.f, 0.f, 0.f, 0.f};
                __builtin_amdgcn_s_setprio(1);
                s = __builtin_amdgcn_mfma_f32_16x16x32_bf16(aH0, cB2[ntile][0][0], s, 0, 0, 0);
                s = __builtin_amdgcn_mfma_f32_16x16x32_bf16(aH1, cB2[ntile][1][0], s, 0, 0, 0);
                s = __builtin_amdgcn_mfma_f32_16x16x32_bf16(aH0, cB2[ntile][0][1], s, 0, 0, 0);
                s = __builtin_amdgcn_mfma_f32_16x16x32_bf16(aH1, cB2[ntile][1][1], s, 0, 0, 0);
                s = __builtin_amdgcn_mfma_f32_16x16x32_bf16(aL0, cB2[ntile][0][0], s, 0, 0, 0);
                s = __builtin_amdgcn_mfma_f32_16x16x32_bf16(aL1, cB2[ntile][1][0], s, 0, 0, 0);
                __builtin_amdgcn_s_setprio(0);
                const float e0 = __expf(s[0]), e1 = __expf(s[1]);
                const float e2 = __expf(s[2]), e3 = __expf(s[3]);
                zp += (e0 + e1) + (e2 + e3);
                short4v pk = { bfbits(e0), bfbits(e1), bfbits(e2), bfbits(e3) };
                // n = T*16+lm, m = ms*16+lq*4  ->  [T][mh][lqp*16+lm] + (lq&1)*8B
                const int T = nq2 * 2 + ntile;
                const int lqp = (ms & 1) * 2 + (lq >> 1);
                Ps4[(((T * 2 + mh) * 64) + lqp * 16 + lm) * 2 + (lq & 1)] = pk;
            }
        }
        // cur-xb (oldest 4 of 10) landed; next tile's 6 stay in flight.
        // lgkmcnt(0): own Ps writes visible before signaling.
        asm volatile("s_waitcnt vmcnt(6) lgkmcnt(0)" ::: "memory");
        __builtin_amdgcn_sched_barrier(0);
        __builtin_amdgcn_s_barrier();            // XB[cur] + all Ps visible
        __builtin_amdgcn_sched_barrier(0);

        // ---- PV: wave = (nq, cq) -> 64 n x 64 c, conflict-free frag reads ----
        const short8* XB = XBs + cur * 2048;
        short8 vb0[4], vb1[4];
#pragma unroll
        for (int q4 = 0; q4 < 4; ++q4) {
            const int ct = cq * 4 + q4;
            vb0[q4] = XB[ct * 64 + lane];
            vb1[q4] = XB[1024 + ct * 64 + lane];
        }
#pragma unroll
        for (int nt2 = 0; nt2 < 4; ++nt2) {
            const int T = nq * 4 + nt2;
            const short8 pa0 = Ps8[(T * 2 + 0) * 64 + lane];
            const short8 pa1 = Ps8[(T * 2 + 1) * 64 + lane];
            __builtin_amdgcn_s_setprio(1);
#pragma unroll
            for (int q4 = 0; q4 < 4; ++q4) {
                acc[nt2][q4] = __builtin_amdgcn_mfma_f32_16x16x32_bf16(
                    pa0, vb0[q4], acc[nt2][q4], 0, 0, 0);
                acc[nt2][q4] = __builtin_amdgcn_mfma_f32_16x16x32_bf16(
                    pa1, vb1[q4], acc[nt2][q4], 0, 0, 0);
            }
            __builtin_amdgcn_s_setprio(0);
        }
    }

    // Z: block reduction -> one atomicAdd
#pragma unroll
    for (int o = 32; o > 0; o >>= 1) zp += __shfl_down(zp, o, 64);
    if (lane == 0) zred[wv] = zp;
    __syncthreads();
    if (t == 0) {
        float zs = 0.f;
#pragma unroll
        for (int wvi = 0; wvi < 8; ++wvi) zs += zred[wvi];
        atomicAdd(&Z[b], zs);
    }

    // O direct stores (sole writer of this (b, n-stripe))
#pragma unroll
    for (int nt2 = 0; nt2 < 4; ++nt2) {
#pragma unroll
        for (int q4 = 0; q4 < 4; ++q4) {
            const int c = cq * 64 + q4 * 16 + lm;
#pragma unroll
            for (int r = 0; r < 4; ++r) {
                const int n = n0 + (nq * 4 + nt2) * 16 + lq * 4 + r;
                O[((size_t)b * HW_ + n) * C_ + c] = acc[nt2][q4][r];
            }
        }
    }
}

extern "C" void kernel_launch(void* const* d_in, const int* in_sizes, int n_in,
                              void* d_out, int out_size, void* d_ws, size_t ws_size,
                              hipStream_t stream)
{
    const float* x   = (const float*)d_in[0];
    const float* wt  = (const float*)d_in[1];
    const float* bt  = (const float*)d_in[2];
    const float* wc  = (const float*)d_in[3];
    const float* bc  = (const float*)d_in[4];
    const float* wbo = (const float*)d_in[5];
    const float* bbo = (const float*)d_in[6];
    const float* wo  = (const float*)d_in[7];
    const float* bo  = (const float*)d_in[8];
    float* out = (float*)d_out;

    uint8_t* w8 = (uint8_t*)d_ws;
    const size_t MB = 1u << 20;
    // [0,16): xtP/xcP (attn inputs)          -> yPk [0,16.5) after attn
    // [16,32): xbB bf16                      (dead after pack_xb)
    // [32,48.5): xPk (dead after conv1)      -> xbP [32,48) -> Wb2 after attn
    // [48,80): O (written by attn)           ; Wb1 at 56 (dead before attn)
    short8* xtPh = (short8*)(w8);
    short8* xtPl = (short8*)(w8 + 4 * MB);
    short8* xcPh = (short8*)(w8 + 8 * MB);
    short8* xcPl = (short8*)(w8 + 12 * MB);
    __hip_bfloat16* xbB = (__hip_bfloat16*)(w8 + 16 * MB);
    short8* xPk  = (short8*)(w8 + 32 * MB);   // 16.5 MB, dead after conv-bottom
    short8* xbP  = (short8*)(w8 + 32 * MB);   // written after xPk dead
    float*  O    = (float*)(w8 + 48 * MB);
    short8* Wb1  = (short8*)(w8 + 56 * MB);   // inside O region (dead before attn)
    short8* Wb2  = (short8*)(w8 + 32 * MB);   // inside xbP region (dead after attn)
    short8* yPk  = (short8*)(w8);             // 16.5 MB, after attn
    float*  Z    = (float*)(w8 + 80 * MB);

    hipMemsetAsync(Z, 0, B_ * sizeof(float), stream);
    k_prep_w<<<dim3(288), 256, 0, stream>>>(wbo, Wb1);
    k_pack_x<<<dim3(528), 256, 0, stream>>>(x, xPk);
    k_conv1x1<<<dim3(16, 8, 8), 256, 0, stream>>>(x, wt, bt, wc, bc,
                                                  xtPh, xtPl, xcPh, xcPl);
    k_conv3x3_mfma<__hip_bfloat16><<<dim3(512), 512, 0, stream>>>(xPk, Wb1, bbo, xbB);
    k_pack_xb<<<dim3(4096), 256, 0, stream>>>(xbB, xbP);
    k_attn_mfma<<<dim3(256), dim3(512), 114720, stream>>>(xtPh, xtPl, xcPh, xcPl,
                                                          xbP, O, Z);
    k_prep_w<<<dim3(288), 256, 0, stream>>>(wo, Wb2);
    k_add_pack<<<dim3(528), 256, 0, stream>>>(x, O, Z, yPk);
    k_conv3x3_mfma<float><<<dim3(512), 512, 0, stream>>>(yPk, Wb2, bo, out);
}

// Round 7
// 389.984 us; speedup vs baseline: 1.2130x; 1.2130x over previous
//
#include <hip/hip_runtime.h>
#include <hip/hip_bf16.h>
#include <type_traits>

constexpr int B_ = 8, C_ = 256, P_ = 64, H_ = 64, W_ = 64, HW_ = 4096;

typedef __attribute__((ext_vector_type(8))) short short8;   // 8 bf16
typedef __attribute__((ext_vector_type(4))) short short4v;  // 4 bf16 (8 B)
typedef __attribute__((ext_vector_type(4))) float f32x4;

__device__ __forceinline__ short bfbits(float f) {
    __hip_bfloat16 h = __float2bfloat16(f);
    return *reinterpret_cast<short*>(&h);
}
__device__ __forceinline__ float bf2f(short s) {
    __hip_bfloat16 h = *reinterpret_cast<__hip_bfloat16*>(&s);
    return (float)h;
}

// async global->LDS, 16B per lane; dst must be wave-uniform base (HW adds lane*16)
#define GLL16(gsrc, ldst)                                                      \
    __builtin_amdgcn_global_load_lds(                                         \
        (const __attribute__((address_space(1))) void*)(gsrc),                \
        (__attribute__((address_space(3))) void*)(ldst), 16, 0, 0)

// ---------------------------------------------------------------------------
// Fragment-linear packed layouts (one wave-load = base + lane*16, contiguous):
//   xtP/xcP [b][tile16][kc2][lane64]x16B : chunk = x[row=tile*16+lm][p=kc*32+lq*8..+8]
//   xbP     [b][g128][ct16][lane64]x16B  : chunk = xb[c=ct*16+lm][m=g*32+lq*8..+8]
//   wbP     [tap9][cb8][cot16][lane64]x16B: chunk = w[co=cot*16+lm][ci=cb*32+lq*8..+8]
// ---------------------------------------------------------------------------

// K0: weight prep, fp32 OIHW -> fragment-linear bf16 wbP. 288 blocks.
__global__ __launch_bounds__(256) void k_prep_w(
    const float* __restrict__ w, short8* __restrict__ wbP)
{
    const int idx = blockIdx.x * 256 + threadIdx.x;      // < 9*8*16*64 = 73728
    const int lane = idx & 63, cot = (idx >> 6) & 15;
    const int cb = (idx >> 10) & 7, tap = idx >> 13;
    const int lm = lane & 15, lq = lane >> 4;
    const int co = cot * 16 + lm, ci0 = cb * 32 + lq * 8;
    short8 v;
#pragma unroll
    for (int k = 0; k < 8; ++k)
        v[k] = bfbits(w[(co * 256 + ci0 + k) * 9 + tap]);
    wbP[idx] = v;
}

// K0c: fp32 [B][C][HW] -> bf16 same-order copy (conv3x3 staging input).
// 2048 blocks; thread: 4 float4 loads -> 2 short8 stores (16 elems).
// 2048*256*16 = 8,388,608 = B*C*HW exactly.
__global__ __launch_bounds__(256) void k_cvt_bf16(
    const float* __restrict__ x, short8* __restrict__ xB)
{
    const size_t i = ((size_t)blockIdx.x * 256 + threadIdx.x) * 16;
    short8 o[2];
#pragma unroll
    for (int q = 0; q < 2; ++q) {
#pragma unroll
        for (int j = 0; j < 2; ++j) {
            const float4 v = *reinterpret_cast<const float4*>(&x[i + q * 8 + j * 4]);
            o[q][j * 4 + 0] = bfbits(v.x);
            o[q][j * 4 + 1] = bfbits(v.y);
            o[q][j * 4 + 2] = bfbits(v.z);
            o[q][j * 4 + 3] = bfbits(v.w);
        }
    }
    short8* dp = (short8*)&xB[i >> 3];
    dp[0] = o[0];
    dp[1] = o[1];
}

// K0b: xb [B][C][HW] bf16 -> fragment-linear xbP. 4096 blocks.
__global__ __launch_bounds__(256) void k_pack_xb(
    const __hip_bfloat16* __restrict__ xb, short8* __restrict__ xbP)
{
    const int tid = blockIdx.x * 256 + threadIdx.x;
    const int lane = tid & 63, wid = tid >> 6;           // wid < 8*128*16
    const int ct = wid & 15, g = (wid >> 4) & 127, b = wid >> 11;
    const int c = ct * 16 + (lane >> 2);
    const int mo = g * 32 + (lane & 3) * 8;
    const short8 v = *reinterpret_cast<const short8*>(
        &xb[((size_t)(b * 256 + c)) * HW_ + mo]);
    xbP[(size_t)wid * 64 + (lane & 3) * 16 + (lane >> 2)] = v;
}

// ---------------------------------------------------------------------------
// K1: 1x1 convs, p-quarter split (grid 16x8x8). Epilogue writes hi/lo bf16
// directly in fragment-linear xtP/xcP order.
// ---------------------------------------------------------------------------
__global__ __launch_bounds__(256) void k_conv1x1(
    const float* __restrict__ x,
    const float* __restrict__ w_top, const float* __restrict__ b_top,
    const float* __restrict__ w_cen, const float* __restrict__ b_cen,
    short8* __restrict__ xtPh, short8* __restrict__ xtPl,
    short8* __restrict__ xcPh, short8* __restrict__ xcPl)
{
    const int b = blockIdx.z;
    const int n = blockIdx.x * 256 + threadIdx.x;
    const int conv = blockIdx.y >> 2, pq = blockIdx.y & 3;
    const int p0 = pq * 16;
    const float* w    = conv ? w_cen : w_top;
    const float* bias = conv ? b_cen : b_top;
    short8* oh = conv ? xcPh : xtPh;
    short8* ol = conv ? xcPl : xtPl;

    const float* xp = x + (size_t)b * C_ * HW_ + n;
    float acc[16];
#pragma unroll
    for (int p = 0; p < 16; ++p) acc[p] = 0.f;

    for (int c = 0; c < C_; c += 4) {
        const float xv0 = xp[(size_t)(c + 0) * HW_];
        const float xv1 = xp[(size_t)(c + 1) * HW_];
        const float xv2 = xp[(size_t)(c + 2) * HW_];
        const float xv3 = xp[(size_t)(c + 3) * HW_];
#pragma unroll
        for (int p = 0; p < 16; ++p) {
            const float4 wv = *reinterpret_cast<const float4*>(&w[(p0 + p) * C_ + c]);
            float a = acc[p];
            a = fmaf(wv.x, xv0, a);
            a = fmaf(wv.y, xv1, a);
            a = fmaf(wv.z, xv2, a);
            a = fmaf(wv.w, xv3, a);
            acc[p] = a;
        }
    }
    const int nt = n >> 4, lmn = n & 15;
    const size_t obase = ((size_t)(b * 256 + nt) * 2 + (pq >> 1)) * 64 + lmn;
#pragma unroll
    for (int jj = 0; jj < 2; ++jj) {
        short8 vh, vl;
#pragma unroll
        for (int k = 0; k < 8; ++k) {
            const float v = acc[jj * 8 + k] + bias[p0 + jj * 8 + k];
            const short hb = bfbits(v);
            vh[k] = hb;
            vl[k] = bfbits(v - bf2f(hb));   // residual for hi/lo split
        }
        const size_t idx = obase + (size_t)(((pq & 1) * 2 + jj) * 16);
        oh[idx] = vh;
        ol[idx] = vl;
    }
}

// ---------------------------------------------------------------------------
// K2/K5: 3x3 conv as implicit GEMM, bf16 MFMA. R13 = R11 structure (merged
// co-halves, 512-thread blocks, grid 512 1D, b==XCD, lane->w coalesced
// staging) with BF16 INPUT: staging reads short4v (8B/lane, half the bytes)
// and stores raw bf16 bits -> zero cvt instructions in the hot loop.
// ---------------------------------------------------------------------------
template <typename OT>
__global__ __launch_bounds__(512, 4) void k_conv3x3_mfma(
    const short* __restrict__ xin, const short8* __restrict__ wbP,
    const float* __restrict__ bias, OT* __restrict__ out)
{
    __shared__ __align__(16) short Xs[3][66][40];
    const int lin = blockIdx.x;                 // 0..511
    const int b = lin & 7, h = lin >> 3;        // b == XCD
    const int t = threadIdx.x;
    const int wave = t >> 6, lane = t & 63;
    const int lm = lane & 15, lq = lane >> 4;
    const int cobase = wave * 32;
    const int cot0 = wave * 2;                  // co-tile index base (co/16)

    f32x4 acc[4][2];   // [n_tile][co_tile]
#pragma unroll
    for (int i = 0; i < 4; ++i)
#pragma unroll
        for (int j = 0; j < 2; ++j) acc[i][j] = f32x4{0.f, 0.f, 0.f, 0.f};

    if (t < 192) {   // zero w-halo columns once (3 r x 2 sides x 32 ci)
        const int r = t >> 6, cc = t & 31, side = (t >> 5) & 1;
        Xs[r][side ? 65 : 0][cc] = 0;
    }

    const short* xbase = xin + (size_t)b * C_ * HW_;

    for (int cb = 0; cb < 8; ++cb) {
        const int ci0 = cb * 32;
        __syncthreads();
        // stage 3 rows x 32 ci x 64 w: 1536 short4 over 512 threads.
        // idx -> (r, ci, wq); consecutive wq -> 128B coalesced segments.
#pragma unroll
        for (int it = 0; it < 3; ++it) {
            const int idx = it * 512 + t;
            const int r = idx >> 9, ci = (idx >> 4) & 31, wq = idx & 15;
            const int hh = h + r - 1;
            short4v v = {0, 0, 0, 0};
            if (hh >= 0 && hh < H_)
                v = *reinterpret_cast<const short4v*>(
                    &xbase[(size_t)(ci0 + ci) * HW_ + hh * W_ + wq * 4]);
            Xs[r][1 + wq * 4 + 0][ci] = v[0];
            Xs[r][1 + wq * 4 + 1][ci] = v[1];
            Xs[r][1 + wq * 4 + 2][ci] = v[2];
            Xs[r][1 + wq * 4 + 3][ci] = v[3];
        }
        __syncthreads();

#pragma unroll 3
        for (int tap = 0; tap < 9; ++tap) {
            const int dh = tap / 3;
            const int dw = tap % 3;
            const short8* wp = wbP + ((size_t)(tap * 8 + cb)) * 1024 + lane;
            short8 af[2];
            af[0] = wp[(cot0 + 0) * 64];
            af[1] = wp[(cot0 + 1) * 64];
            short8 bf[4];
#pragma unroll
            for (int nt = 0; nt < 4; ++nt)
                bf[nt] = *reinterpret_cast<const short8*>(
                    &Xs[dh][nt * 16 + lm + dw][lq * 8]);
#pragma unroll
            for (int nt = 0; nt < 4; ++nt)
#pragma unroll
                for (int ct = 0; ct < 2; ++ct)
                    acc[nt][ct] = __builtin_amdgcn_mfma_f32_16x16x32_bf16(
                        af[ct], bf[nt], acc[nt][ct], 0, 0, 0);
        }
    }

#pragma unroll
    for (int nt = 0; nt < 4; ++nt) {
        const int pos = h * W_ + nt * 16 + lm;
#pragma unroll
        for (int ct = 0; ct < 2; ++ct) {
            const int co = cobase + ct * 16 + lq * 4;
#pragma unroll
            for (int r = 0; r < 4; ++r) {
                const float v = acc[nt][ct][r] + bias[co + r];
                if constexpr (std::is_same<OT, __hip_bfloat16>::value)
                    out[((size_t)(b * C_ + co + r)) * HW_ + pos] = __float2bfloat16(v);
                else
                    out[((size_t)(b * C_ + co + r)) * HW_ + pos] = v;
            }
        }
    }
}

// ---------------------------------------------------------------------------
// K3: fused attention. R10 structure (unchanged): one block per (b, 128-n
// stripe), grid 256, all 64 mt per block, double-buffered XT/XB via
// global_load_lds with counted vmcnt, S^T 2m x 4n wave split, fragment-
// linear Ps. 2 barriers/iter. LDS 114.7 KB, 1 block/CU. b == XCD.
// ---------------------------------------------------------------------------
__global__ __launch_bounds__(512, 2) void k_attn_mfma(
    const short8* __restrict__ xtPh, const short8* __restrict__ xtPl,
    const short8* __restrict__ xcPh, const short8* __restrict__ xcPl,
    const short8* __restrict__ xbP, float* __restrict__ O,
    float* __restrict__ Z)
{
    extern __shared__ __align__(16) char smem[];
    short8* XTs = (short8*)smem;                    // [2][1024]  (2 x 16 KB)
    short8* XBs = (short8*)(smem + 32768);          // [2][2048]  (2 x 32 KB)
    short8* Ps8 = (short8*)(smem + 98304);          // [8 T][2 mh][64]  16 KB
    short4v* Ps4 = (short4v*)(smem + 98304);
    float* zred = (float*)(smem + 114688);

    const int lin = blockIdx.x;                 // 0..255
    const int b = lin & 7, nblk = lin >> 3;     // b == XCD (round-robin dispatch)
    const int n0 = nblk * 128;

    const int t = threadIdx.x, wv = t >> 6, lane = t & 63;
    const int lm = lane & 15, lq = lane >> 4;
    const int mh = wv >> 2, nq2 = wv & 3;       // S^T split: m-half x n-quarter
    const int nq = wv >> 2, cq = wv & 3;        // PV split: n-half x c-quarter

    // Hoisted S^T B-frags: xc for wave's 2 n-tiles (nq2*2, nq2*2+1)
    short8 cB2[2][2][2];   // [ntile][kc][hilo]
#pragma unroll
    for (int ntile = 0; ntile < 2; ++ntile) {
        const int gt = nblk * 8 + nq2 * 2 + ntile;
        const size_t base = ((size_t)(b * 256 + gt) * 2) * 64 + lane;
        cB2[ntile][0][0] = xcPh[base];
        cB2[ntile][1][0] = xcPh[base + 64];
        cB2[ntile][0][1] = xcPl[base];
        cB2[ntile][1][1] = xcPl[base + 64];
    }
    asm volatile("s_waitcnt vmcnt(0)" ::: "memory");   // clean slate for counts

    auto stage = [&](int smt, int bufi) {
        short8* XT = XTs + bufi * 1024;
        short8* XB = XBs + bufi * 2048;
        const size_t abase = ((size_t)(b * 512 + smt * 8)) * 64;
#pragma unroll
        for (int k = 0; k < 2; ++k) {            // 2 xt chunks (issued FIRST)
            const int c = wv * 2 + k, ms = c >> 2, part = c & 3;
            const short8* src = (part < 2 ? xtPh : xtPl)
                                + abase + ms * 128 + (part & 1) * 64 + lane;
            GLL16(src, XT + c * 64);
        }
        const size_t p8 = ((size_t)(b * 2048 + smt * 32)) * 64;
#pragma unroll
        for (int k = 0; k < 4; ++k) {            // 4 xb chunks
            const int e = k * 512 + wv * 64;
            GLL16(xbP + p8 + e + lane, XB + e);
        }
    };
    stage(0, 0);                                 // prologue: 6 loads in flight

    f32x4 acc[4][4];   // O partial [n-subtile within half][c-tile within quarter]
#pragma unroll
    for (int i = 0; i < 4; ++i)
#pragma unroll
        for (int jj = 0; jj < 4; ++jj) acc[i][jj] = f32x4{0.f, 0.f, 0.f, 0.f};
    float zp = 0.f;

    for (int mt = 0; mt < 64; ++mt) {
        const int cur = mt & 1;
        // own cur-xt (oldest 2 of 6) landed; cur-xb still in flight
        asm volatile("s_waitcnt vmcnt(4)" ::: "memory");
        __builtin_amdgcn_sched_barrier(0);
        __builtin_amdgcn_s_barrier();            // all waves' xt staged; all
        __builtin_amdgcn_sched_barrier(0);       // finished prev PV reads
        // issue next tile's 6 loads into the other buffer (wrap keeps counts
        // uniform; final wrap-stage is harmless)
        stage((mt + 1) & 63, cur ^ 1);

        // ---- S^T: wave = (mh, nq2) -> 32 m x 32 n of this mt's 64x128 ----
        const short8* XT = XTs + cur * 1024;
#pragma unroll
        for (int ms2 = 0; ms2 < 2; ++ms2) {
            const int ms = mh * 2 + ms2;
            const short8 aH0 = XT[(ms * 4 + 0) * 64 + lane];
            const short8 aH1 = XT[(ms * 4 + 1) * 64 + lane];
            const short8 aL0 = XT[(ms * 4 + 2) * 64 + lane];
            const short8 aL1 = XT[(ms * 4 + 3) * 64 + lane];
#pragma unroll
            for (int ntile = 0; ntile < 2; ++ntile) {
                f32x4 s = {0.f, 0.f, 0.f, 0.f};
                __builtin_amdgcn_s_setprio(1);
                s = __builtin_amdgcn_mfma_f32_16x16x32_bf16(aH0, cB2[ntile][0][0], s, 0, 0, 0);
                s = __builtin_amdgcn_mfma_f32_16x16x32_bf16(aH1, cB2[ntile][1][0], s, 0, 0, 0);
                s = __builtin_amdgcn_mfma_f32_16x16x32_bf16(aH0, cB2[ntile][0][1], s, 0, 0, 0);
                s = __builtin_amdgcn_mfma_f32_16x16x32_bf16(aH1, cB2[ntile][1][1], s, 0, 0, 0);
                s = __builtin_amdgcn_mfma_f32_16x16x32_bf16(aL0, cB2[ntile][0][0], s, 0, 0, 0);
                s = __builtin_amdgcn_mfma_f32_16x16x32_bf16(aL1, cB2[ntile][1][0], s, 0, 0, 0);
                __builtin_amdgcn_s_setprio(0);
                const float e0 = __expf(s[0]), e1 = __expf(s[1]);
                const float e2 = __expf(s[2]), e3 = __expf(s[3]);
                zp += (e0 + e1) + (e2 + e3);
                short4v pk = { bfbits(e0), bfbits(e1), bfbits(e2), bfbits(e3) };
                // n = T*16+lm, m = ms*16+lq*4  ->  [T][mh][lqp*16+lm] + (lq&1)*8B
                const int T = nq2 * 2 + ntile;
                const int lqp = (ms & 1) * 2 + (lq >> 1);
                Ps4[(((T * 2 + mh) * 64) + lqp * 16 + lm) * 2 + (lq & 1)] = pk;
            }
        }
        // cur-xb (oldest 4 of 10) landed; next tile's 6 stay in flight.
        // lgkmcnt(0): own Ps writes visible before signaling.
        asm volatile("s_waitcnt vmcnt(6) lgkmcnt(0)" ::: "memory");
        __builtin_amdgcn_sched_barrier(0);
        __builtin_amdgcn_s_barrier();            // XB[cur] + all Ps visible
        __builtin_amdgcn_sched_barrier(0);

        // ---- PV: wave = (nq, cq) -> 64 n x 64 c, conflict-free frag reads ----
        const short8* XB = XBs + cur * 2048;
        short8 vb0[4], vb1[4];
#pragma unroll
        for (int q4 = 0; q4 < 4; ++q4) {
            const int ct = cq * 4 + q4;
            vb0[q4] = XB[ct * 64 + lane];
            vb1[q4] = XB[1024 + ct * 64 + lane];
        }
#pragma unroll
        for (int nt2 = 0; nt2 < 4; ++nt2) {
            const int T = nq * 4 + nt2;
            const short8 pa0 = Ps8[(T * 2 + 0) * 64 + lane];
            const short8 pa1 = Ps8[(T * 2 + 1) * 64 + lane];
            __builtin_amdgcn_s_setprio(1);
#pragma unroll
            for (int q4 = 0; q4 < 4; ++q4) {
                acc[nt2][q4] = __builtin_amdgcn_mfma_f32_16x16x32_bf16(
                    pa0, vb0[q4], acc[nt2][q4], 0, 0, 0);
                acc[nt2][q4] = __builtin_amdgcn_mfma_f32_16x16x32_bf16(
                    pa1, vb1[q4], acc[nt2][q4], 0, 0, 0);
            }
            __builtin_amdgcn_s_setprio(0);
        }
    }

    // Z: block reduction -> one atomicAdd
#pragma unroll
    for (int o = 32; o > 0; o >>= 1) zp += __shfl_down(zp, o, 64);
    if (lane == 0) zred[wv] = zp;
    __syncthreads();
    if (t == 0) {
        float zs = 0.f;
#pragma unroll
        for (int wvi = 0; wvi < 8; ++wvi) zs += zred[wvi];
        atomicAdd(&Z[b], zs);
    }

    // O direct stores (sole writer of this (b, n-stripe))
#pragma unroll
    for (int nt2 = 0; nt2 < 4; ++nt2) {
#pragma unroll
        for (int q4 = 0; q4 < 4; ++q4) {
            const int c = cq * 64 + q4 * 16 + lm;
#pragma unroll
            for (int r = 0; r < 4; ++r) {
                const int n = n0 + (nq * 4 + nt2) * 16 + lq * 4 + r;
                O[((size_t)b * HW_ + n) * C_ + c] = acc[nt2][q4][r];
            }
        }
    }
}

// ---------------------------------------------------------------------------
// K4: yB = bf16(x + O*(1/Z[b])) (flat reinterpretation add, bf16 output —
// numerically identical to the old fp32 y since conv staging truncated to
// bf16 anyway; halves the write traffic and feeds conv2 directly).
// ---------------------------------------------------------------------------
__global__ __launch_bounds__(256) void k_add_bf16(
    const float* __restrict__ x, const float* __restrict__ o,
    const float* __restrict__ Z, short4v* __restrict__ yB)
{
    const int bidx = blockIdx.x;
    const float invZ = 1.0f / Z[bidx >> 10];
    const size_t i = ((size_t)bidx * 256 + threadIdx.x) * 4;
    const float4 a = *reinterpret_cast<const float4*>(&x[i]);
    const float4 b = *reinterpret_cast<const float4*>(&o[i]);
    short4v r{bfbits(fmaf(b.x, invZ, a.x)), bfbits(fmaf(b.y, invZ, a.y)),
              bfbits(fmaf(b.z, invZ, a.z)), bfbits(fmaf(b.w, invZ, a.w))};
    yB[i >> 2] = r;
}

extern "C" void kernel_launch(void* const* d_in, const int* in_sizes, int n_in,
                              void* d_out, int out_size, void* d_ws, size_t ws_size,
                              hipStream_t stream)
{
    const float* x   = (const float*)d_in[0];
    const float* wt  = (const float*)d_in[1];
    const float* bt  = (const float*)d_in[2];
    const float* wc  = (const float*)d_in[3];
    const float* bc  = (const float*)d_in[4];
    const float* wbo = (const float*)d_in[5];
    const float* bbo = (const float*)d_in[6];
    const float* wo  = (const float*)d_in[7];
    const float* bo  = (const float*)d_in[8];
    float* out = (float*)d_out;

    uint8_t* w8 = (uint8_t*)d_ws;
    const size_t MB = 1u << 20;
    // [0,16): xtP/xcP (attn inputs; dead after attn)
    // [16,32): xbB bf16 (conv1 out; dead after pack_xb) -> yB after attn
    // [32,48): xbP (dead after attn) -> Wb2 overlays after attn
    // [48,80): O (attn out); Wb1 at 48 (dead before attn); xB at [64,80)
    //          (read only by conv1, which completes before attn writes O)
    short8* xtPh = (short8*)(w8);
    short8* xtPl = (short8*)(w8 + 4 * MB);
    short8* xcPh = (short8*)(w8 + 8 * MB);
    short8* xcPl = (short8*)(w8 + 12 * MB);
    __hip_bfloat16* xbB = (__hip_bfloat16*)(w8 + 16 * MB);
    short8* xbP  = (short8*)(w8 + 32 * MB);
    float*  O    = (float*)(w8 + 48 * MB);
    short8* Wb1  = (short8*)(w8 + 48 * MB);   // inside O region (dead before attn)
    short8* xB   = (short8*)(w8 + 64 * MB);   // bf16 x copy (conv1 staging input)
    short8* Wb2  = (short8*)(w8 + 32 * MB);   // inside xbP region (dead after attn)
    short4v* yB  = (short4v*)(w8 + 16 * MB);  // bf16 residual sum (conv2 input)
    float*  Z    = (float*)(w8 + 80 * MB);

    hipMemsetAsync(Z, 0, B_ * sizeof(float), stream);
    k_prep_w<<<dim3(288), 256, 0, stream>>>(wbo, Wb1);
    k_cvt_bf16<<<dim3(2048), 256, 0, stream>>>(x, xB);
    k_conv1x1<<<dim3(16, 8, 8), 256, 0, stream>>>(x, wt, bt, wc, bc,
                                                  xtPh, xtPl, xcPh, xcPl);
    k_conv3x3_mfma<__hip_bfloat16><<<dim3(512), 512, 0, stream>>>(
        (const short*)xB, Wb1, bbo, xbB);
    k_pack_xb<<<dim3(4096), 256, 0, stream>>>(xbB, xbP);
    k_attn_mfma<<<dim3(256), dim3(512), 114720, stream>>>(xtPh, xtPl, xcPh, xcPl,
                                                          xbP, O, Z);
    k_prep_w<<<dim3(288), 256, 0, stream>>>(wo, Wb2);
    k_add_bf16<<<dim3(8192), 256, 0, stream>>>(x, O, Z, yB);
    k_conv3x3_mfma<float><<<dim3(512), 512, 0, stream>>>(
        (const short*)yB, Wb2, bo, out);
}